// Round 10
// baseline (771.686 us; speedup 1.0000x reference)
//
#include <hip/hip_runtime.h>
#include <math.h>

// Problem constants (from reference)
#define B_   8
#define T_   128
#define E_   256
#define H_   512
#define G_   2048
#define NWG  256           // 1 WG per CU (146KB LDS), all co-resident
#define NTHR 512           // 8 waves

typedef unsigned int u32;
typedef unsigned long long u64;

// ---------------------------------------------------------------------------
// ALGEBRA (unchanged): softmax sums to 1 over t and h_shared is t-invariant =>
// Rt == h_last; attention path dead. Batches independent -> 8 rings of 32 WGs
// (ring = blockIdx&7, slot = blockIdx>>3 owns h-cols 16s..16s+15).
//
// R18 = R17 (scratch-free, 586us, step 2.29us) + XCD-LOCAL L2 EXCHANGE.
// R17 evidence: step time pinned at ~2.2us by MALL publish->poll visibility
// (R15/R17 compute trims moved nothing). The only structural lever left is
// the exchange itself. Re-audit with the scratch bug known:
//  - R13's L2-probe failure: rings were blockIdx-based => cross-XCD pairs;
//    consumer's L2 holds a stale CLEAN line that is never invalidated (no
//    cross-XCD coherence) => probes must fail. NOT evidence against same-XCD.
//  - R12's corruption: 2-bit parity tag aliases under >=4-gen lag.
// The clean experiment (verified-pure rings + exact-gen tags + same-XCD L2)
// has never run. Under round-robin placement ring b=blockIdx&7 IS XCD-pure.
//
// Transport (this round):
//  - 8B records (value|gen<<32); accept ONLY exact gen (+LSB parity
//    anti-tear) => any staleness = retry, never corruption.
//  - publish: 16-lane plain global_store_dwordx2 to imgL2 (lands in the
//    producer's L2 = consumer's L2 if ring pure) AND 16-lane agent-scope
//    store to imgMall (guaranteed). One line = one writer instruction.
//  - poll: if ring verified pure (runtime XCC_ID table + vote, timeout =>
//    impure) and path healthy: spin <=96 sc0 loads on imgL2 (XCD-local,
//    ~200cy each, no fabric storm). Timeout => MALL rescue (R17 path,
//    s_sleep(1)) + health-1 (init 6; success resets; 0 => L2 off forever).
//    Bounded worst-case waste ~50us. If XCC_ID lies => false-pure => probes
//    fail => health kills path => correct at ~R17 speed.
// Step structure, dot, gates: R17 verbatim (verified; wreg compile-time
// indexed, no scratch).
//
// No-lap (R8 argument) unchanged. ws: imgL2 u64[2][8][512] @0 (64KB),
// imgMall same @64KB, XCD table u32[256] @128KB; init all 0xFFFFFFFF
// (gen 0xFFFFFFFF never matches; publishes use gens 1..255).
//
// LDS = Wl 128K + Xl 16K + h_lds 2K + hOut 64B + flag ~= 146 KiB.
// ---------------------------------------------------------------------------

__device__ __forceinline__ float sigf(float x) {
  return 1.0f / (1.0f + __expf(-x));
}
__device__ __forceinline__ float tanh_f(float x) {
  float xx = fminf(15.0f, fmaxf(-15.0f, x));
  float e  = __expf(2.0f * xx);
  return (e - 1.0f) / (e + 1.0f);
}

__device__ __forceinline__ unsigned short f2bf(float x) {
  u32 u = __float_as_uint(x);
  u += 0x7fffu + ((u >> 16) & 1u);
  return (unsigned short)(u >> 16);
}
__device__ __forceinline__ float bf2f(unsigned short s) {
  return __uint_as_float(((u32)s) << 16);
}

// ws: 33024 u32 = two u64[8192] mailboxes + u32[256] XCD table, all 0xFFFFFFFF.
__global__ void init_ws(u32* w) {
  int i = blockIdx.x * blockDim.x + threadIdx.x;
  if (i < 33024) w[i] = 0xFFFFFFFFu;
}

// LDS index swizzles (used consistently by all readers/writers)
__device__ __forceinline__ int wl_idx(int k, int c) { return k * 64 + (c ^ ((k >> 4) & 31)); }
__device__ __forceinline__ int xl_idx(int c, int t) { return c * T_ + (t ^ ((c & 31) << 1)); }

// Stage k-major slice: Wl[k][c] = W[k][(c>>4)*H + s*16 + (c&15)], k < rows
__device__ __forceinline__ void stage_W(const float* __restrict__ W, int rows,
                                        int s, float* __restrict__ Wl) {
  for (int idx = threadIdx.x; idx < rows * 64; idx += NTHR) {
    int k = idx >> 6, c = idx & 63;
    Wl[wl_idx(k, c)] = W[k * G_ + ((c >> 4) * H_ + s * 16 + (c & 15))];
  }
}

__attribute__((amdgpu_waves_per_eu(2)))
__global__ __launch_bounds__(NTHR, 1) void lstm_all(
    const int* __restrict__ tokens, const float* __restrict__ embed,
    const float* __restrict__ Wih_s, const float* __restrict__ Whh_s,
    const float* __restrict__ b_s,
    const float* __restrict__ Wih_t, const float* __restrict__ Whh_t,
    const float* __restrict__ Wmh_t, const float* __restrict__ b_t,
    float* __restrict__ out, u64* __restrict__ ws) {
  __shared__ float Wl[H_ * 64];            // 128 KiB, k-major weight slice (swizzled)
  __shared__ unsigned short Xl[64 * T_];   // 16 KiB, bf16 X (swizzled)
  __shared__ float h_lds[H_];              // 2 KiB, staged h
  __shared__ float hOut[16];               // this slot's 16 new h values
  __shared__ u32 flagLds;

  u64* __restrict__ imgL2   = ws;          // opportunistic (plain store / sc0 load)
  u64* __restrict__ imgMall = ws + 8192;   // guaranteed (agent scope)
  u32* __restrict__ tbl     = (u32*)(ws + 16384);  // XCC_ID table[256]

  const int tid = threadIdx.x;
  const int l   = tid & 63;                // lane
  const int wv  = tid >> 6;                // wave: owns h-cols {2wv, 2wv+1} (local)
  const int b   = blockIdx.x & 7;          // ring = batch (guaranteed coverage)
  const int s   = blockIdx.x >> 3;         // slot: h-cols 16s..16s+15
  const int kch = l >> 3;                  // k-chunk 0..7 (64 k each)
  const int cc  = ((l & 7) >> 1) * 16 + 2 * wv + (l & 1);  // this lane's gate col
  const int d   = l & 1;                   // h-col parity within wave
  const unsigned bH = (unsigned)(b * H_);

  // ---- purity detection: is ring b on one XCD? (XCC_ID imm 6164 = id20|w4)
  const u32 xcd = ((u32)__builtin_amdgcn_s_getreg(6164)) & 15u;
  if (tid == 0)
    __hip_atomic_store(tbl + blockIdx.x, xcd, __ATOMIC_RELAXED,
                       __HIP_MEMORY_SCOPE_AGENT);
  u32 vote = 1u;
  if (tid < 32) {                          // lane t checks slot t of our ring
    int wd2 = 1 << 20;
    u32 v;
    for (;;) {
      v = __hip_atomic_load(tbl + b + 8 * tid, __ATOMIC_RELAXED,
                            __HIP_MEMORY_SCOPE_AGENT);
      if (v != 0xFFFFFFFFu || --wd2 < 0) break;
      __builtin_amdgcn_s_sleep(1);
    }
    vote = (v == xcd && wd2 >= 0) ? 1u : 0u;  // timeout => impure (safe)
  }
  if (tid < 64) {
    unsigned long long bal = __ballot(vote != 0u);
    if (tid == 0) flagLds = (bal == ~0ull) ? 1u : 0u;
  }
  __syncthreads();
  int l2cnt = (flagLds != 0u) ? 6 : 0;     // fast-path health (0 = off)

  int wd = 1 << 20;                        // watchdog: MALL retries/thread
  float wreg[64];                          // pinned per-lane weight K-slice

  // ---- X phase: Xl[c][t] (bf16) = emb[b,t] @ Wih[:,col(c)] + bias[col(c)]
  auto computeX = [&](const float* __restrict__ Wih, const float* __restrict__ bias) {
    stage_W(Wih, E_, s, Wl);               // 256x64 into Wl (fits)
    __syncthreads();
    const int t = tid >> 2, grp = tid & 3; // grp = gate; 16 cols each
    const int tok = tokens[b * T_ + t];
    const float4* er = (const float4*)(embed + (size_t)tok * E_);
    float acc[16];
#pragma unroll
    for (int j = 0; j < 16; ++j) acc[j] = bias[grp * H_ + s * 16 + j];
    for (int e4 = 0; e4 < E_ / 4; ++e4) {
      float4 em = er[e4];
#pragma unroll
      for (int eo = 0; eo < 4; ++eo) {
        float ev = reinterpret_cast<const float*>(&em)[eo];
        const int k = e4 * 4 + eo;
#pragma unroll
        for (int j = 0; j < 16; ++j) acc[j] += ev * Wl[wl_idx(k, grp * 16 + j)];
      }
    }
#pragma unroll
    for (int j = 0; j < 16; ++j) Xl[xl_idx(grp * 16 + j, t)] = f2bf(acc[j]);
  };

  // Load the lane's 64 weights in ROTATED order so do_dot's register indices
  // are all compile-time (scratch-free; the R9-R16 lesson).
  auto load_wreg = [&] {
#pragma unroll
    for (int i = 0; i < 16; ++i) {
      const int q = (i + 2 * kch) & 15;    // runtime math feeding an LDS ADDR — ok
#pragma unroll
      for (int j = 0; j < 4; ++j)
        wreg[i * 4 + j] = Wl[wl_idx(kch * 64 + q * 4 + j, cc)];
    }
#pragma unroll
    for (int kk = 0; kk < 64; ++kk) asm volatile("" : "+v"(wreg[kk]));  // pin
  };

  // Per-THREAD poll of OWN record. L2 fast path (if pure+healthy): sc0 spins,
  // XCD-local. Timeout -> MALL rescue (proven) + health decay.
  auto poll_own = [&](unsigned gen) {
    const u32 par = (gen >> 1) & 1u;
    const unsigned idx = (gen & 1u) * 4096u + bH + (unsigned)tid;
    u32 val = 0u;
    bool got = false;
    if (l2cnt > 0) {
      const u64* p = imgL2 + idx;
      for (int i = 0; i < 96; ++i) {
        u64 v;
        asm volatile("global_load_dwordx2 %0, %1, off sc0\n\ts_waitcnt vmcnt(0)"
                     : "=v"(v) : "v"(p) : "memory");
        if ((u32)(v >> 32) == gen && (((u32)v) & 1u) == par) {
          val = (u32)v; got = true; break;
        }
      }
      l2cnt = got ? 6 : (l2cnt - 1);       // success resets; 6 strikes => off
    }
    if (!got) {
      const u64* q = imgMall + idx;
      for (;;) {
        u64 v = __hip_atomic_load(q, __ATOMIC_RELAXED, __HIP_MEMORY_SCOPE_AGENT);
        if ((u32)(v >> 32) == gen && (((u32)v) & 1u) == par) { val = (u32)v; break; }
        if (--wd < 0) break;               // fail fast, not hang
        __builtin_amdgcn_s_sleep(1);
      }
    }
    h_lds[tid] = __uint_as_float(val);     // tag bit kept (1 ulp, harmless)
  };

  // Dual publish of one record (called by tid<16 only): plain L2 store
  // (XCD-local rendezvous) + agent MALL store (guaranteed).
  auto publish = [&](unsigned gen, int fi, float hn) {
    u32 v32 = (__float_as_uint(hn) & ~1u) | ((gen >> 1) & 1u);
    u64 pack = ((u64)gen << 32) | (u64)v32;
    const unsigned idx = (gen & 1u) * 4096u + bH + (unsigned)fi;
    u64* p = imgL2 + idx;
    asm volatile("global_store_dwordx2 %0, %1, off" :: "v"(p), "v"(pack) : "memory");
    __hip_atomic_store(imgMall + idx, pack, __ATOMIC_RELAXED,
                       __HIP_MEMORY_SCOPE_AGENT);
  };

  // Full dot for this lane's col over shared h_lds (R17-verified, scratch-free).
  auto do_dot = [&]() -> float {
    float a0 = 0.f, a1 = 0.f, a2 = 0.f, a3 = 0.f;
    const float4* h4 = (const float4*)(h_lds + kch * 64);
#pragma unroll
    for (int i = 0; i < 16; ++i) {
      const int q = (i + 2 * kch) & 15;    // matches load_wreg's rotation
      float4 hv = h4[q];
      a0 += hv.x * wreg[i * 4 + 0];
      a1 += hv.y * wreg[i * 4 + 1];
      a2 += hv.z * wreg[i * 4 + 2];
      a3 += hv.w * wreg[i * 4 + 3];
    }
    float sum = (a0 + a1) + (a2 + a3);
    sum += __shfl_xor(sum, 8);
    sum += __shfl_xor(sum, 16);
    sum += __shfl_xor(sum, 32);
    return sum;                            // full pre-dot for col cc, all lanes
  };

  // ---------------- Phase A1 + shared weights
  computeX(Wih_s, b_s);
  __syncthreads();
  stage_W(Whh_s, H_, s, Wl);
  __syncthreads();
  load_wreg();

  float c_reg = 0.f, Mreg = 0.f;

  // ---------------- Phase B: shared LSTM; publishes gens 1..128.
  for (int t = 0; t < T_; ++t) {
    float pre = 0.f;
    if (t > 0) {
      poll_own((unsigned)t);
      __syncthreads();                     // barrier 1: h_lds complete
      pre = do_dot();
    }
    if (l < 8) pre += bf2f(Xl[xl_idx(cc, t)]);   // only shfl sources need X
    float gi = __shfl(pre, d),     gf = __shfl(pre, 2 + d),
          gg = __shfl(pre, 4 + d), go = __shfl(pre, 6 + d);
    float cn = sigf(gf) * c_reg + sigf(gi) * tanh_f(gg);
    float hn = sigf(go) * tanh_f(cn);
    c_reg = cn;
    if (l < 2) hOut[2 * wv + l] = hn;      // wave owns h-cols s*16+2wv+{0,1}
    __syncthreads();                       // barrier 2: hOut complete
    if (tid < 16)                          // single-writer publish (R8 rule)
      publish((unsigned)t + 1u, s * 16 + tid, hOut[tid]);
  }

  // ---------------- M = h_last @ Wmh_t (consume gen 128)
  __syncthreads();
  stage_W(Wmh_t, H_, s, Wl);
  __syncthreads();
  load_wreg();
  poll_own(128u);
  __syncthreads();
  Mreg = do_dot();                         // M for col cc (consistent replicas)

  // ---------------- Phase A2 + task weights
  __syncthreads();
  computeX(Wih_t, b_t);
  __syncthreads();
  stage_W(Whh_t, H_, s, Wl);
  __syncthreads();
  load_wreg();

  // ---------------- Phase C: task LSTM; gens 129..255; out every step
  c_reg = 0.f;
  for (int t = 0; t < T_; ++t) {
    float pre = 0.f;
    if (t > 0) {
      poll_own(128u + (unsigned)t);
      __syncthreads();                     // barrier 1
      pre = do_dot();
    }
    if (l < 8) pre += bf2f(Xl[xl_idx(cc, t)]) + Mreg;
    float gi = __shfl(pre, d),     gf = __shfl(pre, 2 + d),
          gg = __shfl(pre, 4 + d), go = __shfl(pre, 6 + d);
    float cn = sigf(gf) * c_reg + sigf(gi) * tanh_f(gg);
    float hn = sigf(go) * tanh_f(cn);
    c_reg = cn;
    if (l < 2) hOut[2 * wv + l] = hn;
    __syncthreads();                       // barrier 2
    if (tid < 16) {                        // publish FIRST (ring-critical), then out
      if (t < T_ - 1)
        publish(129u + (unsigned)t, s * 16 + tid, hOut[tid]);
      out[b * (T_ * H_) + t * H_ + s * 16 + tid] = hOut[tid];  // 64B coalesced
    }
  }
}

extern "C" void kernel_launch(void* const* d_in, const int* in_sizes, int n_in,
                              void* d_out, int out_size, void* d_ws, size_t ws_size,
                              hipStream_t stream) {
  const int*   tokens = (const int*)d_in[0];
  // d_in[1] = TASK (unused)
  const float* embed  = (const float*)d_in[2];
  const float* Wih_s  = (const float*)d_in[3];
  const float* Whh_s  = (const float*)d_in[4];
  const float* b_s    = (const float*)d_in[5];
  // d_in[6..9] = Ws_w, Ws_b, Us_w, Us_b -> dead (attention collapses)
  const float* Wih_t  = (const float*)d_in[10];
  const float* Whh_t  = (const float*)d_in[11];
  const float* Wmh_t  = (const float*)d_in[12];
  const float* b_t    = (const float*)d_in[13];
  float* out = (float*)d_out;

  hipLaunchKernelGGL(init_ws, dim3(33), dim3(1024), 0, stream, (u32*)d_ws);
  hipLaunchKernelGGL(lstm_all, dim3(NWG), dim3(NTHR), 0, stream,
                     tokens, embed, Wih_s, Whh_s, b_s,
                     Wih_t, Whh_t, Wmh_t, b_t, out, (u64*)d_ws);
}

// Round 11
// 659.411 us; speedup vs baseline: 1.1703x; 1.1703x over previous
//
#include <hip/hip_runtime.h>
#include <math.h>

// Problem constants (from reference)
#define B_   8
#define T_   128
#define E_   256
#define H_   512
#define G_   2048
#define NWG  256           // 1 WG per CU (146KB LDS), all co-resident
#define NTHR 512           // 8 waves

typedef unsigned int u32;

// ---------------------------------------------------------------------------
// ALGEBRA (unchanged): softmax sums to 1 over t and h_shared is t-invariant =>
// Rt == h_last; attention path dead. Batches independent -> 8 rings of 32 WGs
// (ring = blockIdx&7, slot = blockIdx>>3 owns h-cols 16s..16s+15).
//
// R19 = R17 (best: 586us) + 2-DEEP PIPELINED POLL.
// Settled facts from R9-R18:
//  - MALL (agent scope) is the ONLY exchange transport. L2 rendezvous tested
//    cleanly in R18 (pure rings + exact-gen tags): SLOWER (693us). Closed.
//  - One mailbox line = one store instruction from one wave (R14: 4 writers
//    /line = 4x). Publish = single 16-lane 64B store.
//  - No runtime-indexed register arrays (R9-R16 scratch bug: ~900MB phantom
//    FETCH+WRITE, 3x time). wreg indices all compile-time.
//  - FETCH_SIZE counts HBM only; mailbox polls are MALL-resident (invisible).
//    R17's 73MB = weight staging. Step time = latency, not traffic.
// R17 step (2.31us) = store visibility (~0.6-0.9us, physics) + poll
// discovery (~0.4us: C poll = DEPENDENT load chain, sampling period = full
// MALL latency ~900cy; barrier1 takes max slack over 512 threads ~ a full
// period) + compute (~0.5us). This round halves the sampling period: asm
// poll with TWO staggered outstanding loads (primed s_sleep 6 apart,
// checked alternately with s_waitcnt vmcnt(1)). Loads use sc0 sc1 (full
// bypass -> MALL direct; cannot be stale vs agent-scope publish). Bounded
// 512 iterations; timeout -> proven __hip_atomic_load fallback + asm path
// disabled permanently (fail-safe, not fail-slow).
//
// Transport (R8/R17 proven): 4B records, in-band mantissa-LSB parity tag
// (gen>>1)&1, buffer gen&1; per-thread poll of OWN float; publish = ONE
// 16-lane 64B agent store. No-lap: a WG publishes g+1 only after its barrier
// confirmed all 512 of g validated => nobody overwrites a gen being read;
// parity distinguishes g from g-2. init: buf0 LSB=0, buf1 LSB=1.
//
// LDS = Wl 128K (f32, XOR-swizzle c^((k>>4)&31)) + Xl 16K (bf16, swizzled)
// + h_lds 2K + hOut 64B ~= 146 KiB.
// ---------------------------------------------------------------------------

__device__ __forceinline__ float sigf(float x) {
  return 1.0f / (1.0f + __expf(-x));
}
__device__ __forceinline__ float tanh_f(float x) {
  float xx = fminf(15.0f, fmaxf(-15.0f, x));
  float e  = __expf(2.0f * xx);
  return (e - 1.0f) / (e + 1.0f);
}

__device__ __forceinline__ unsigned short f2bf(float x) {
  u32 u = __float_as_uint(x);
  u += 0x7fffu + ((u >> 16) & 1u);
  return (unsigned short)(u >> 16);
}
__device__ __forceinline__ float bf2f(unsigned short s) {
  return __uint_as_float(((u32)s) << 16);
}

// img: u32[2][8][512] = 32KB at ws start (R8 layout)
__global__ void init_ws(u32* w) {
  int i = blockIdx.x * blockDim.x + threadIdx.x;
  if (i < 4096)      w[i] = 0u;   // buf0: tag 0
  else if (i < 8192) w[i] = 1u;   // buf1: tag 1
}

// LDS index swizzles (used consistently by all readers/writers)
__device__ __forceinline__ int wl_idx(int k, int c) { return k * 64 + (c ^ ((k >> 4) & 31)); }
__device__ __forceinline__ int xl_idx(int c, int t) { return c * T_ + (t ^ ((c & 31) << 1)); }

// Stage k-major slice: Wl[k][c] = W[k][(c>>4)*H + s*16 + (c&15)], k < rows
__device__ __forceinline__ void stage_W(const float* __restrict__ W, int rows,
                                        int s, float* __restrict__ Wl) {
  for (int idx = threadIdx.x; idx < rows * 64; idx += NTHR) {
    int k = idx >> 6, c = idx & 63;
    Wl[wl_idx(k, c)] = W[k * G_ + ((c >> 4) * H_ + s * 16 + (c & 15))];
  }
}

__attribute__((amdgpu_waves_per_eu(2)))
__global__ __launch_bounds__(NTHR, 1) void lstm_all(
    const int* __restrict__ tokens, const float* __restrict__ embed,
    const float* __restrict__ Wih_s, const float* __restrict__ Whh_s,
    const float* __restrict__ b_s,
    const float* __restrict__ Wih_t, const float* __restrict__ Whh_t,
    const float* __restrict__ Wmh_t, const float* __restrict__ b_t,
    float* __restrict__ out, u32* __restrict__ img) {
  __shared__ float Wl[H_ * 64];            // 128 KiB, k-major weight slice (swizzled)
  __shared__ unsigned short Xl[64 * T_];   // 16 KiB, bf16 X (swizzled)
  __shared__ float h_lds[H_];              // 2 KiB, staged h
  __shared__ float hOut[16];               // this slot's 16 new h values

  const int tid = threadIdx.x;
  const int l   = tid & 63;                // lane
  const int wv  = tid >> 6;                // wave: owns h-cols {2wv, 2wv+1} (local)
  const int b   = blockIdx.x & 7;          // ring = batch (guaranteed coverage)
  const int s   = blockIdx.x >> 3;         // slot: h-cols 16s..16s+15
  const int kch = l >> 3;                  // k-chunk 0..7 (64 k each)
  const int cc  = ((l & 7) >> 1) * 16 + 2 * wv + (l & 1);  // this lane's gate col
  const int d   = l & 1;                   // h-col parity within wave
  const int bH  = b * H_;

  int  wd       = 1 << 20;                 // watchdog: fallback retries/thread
  bool fastOk   = true;                    // pipelined-poll health (fail-safe)
  float wreg[64];                          // pinned per-lane weight K-slice
                                           // (ROTATED storage, see load_wreg)

  // ---- X phase: Xl[c][t] (bf16) = emb[b,t] @ Wih[:,col(c)] + bias[col(c)]
  auto computeX = [&](const float* __restrict__ Wih, const float* __restrict__ bias) {
    stage_W(Wih, E_, s, Wl);               // 256x64 into Wl (fits)
    __syncthreads();
    const int t = tid >> 2, grp = tid & 3; // grp = gate; 16 cols each
    const int tok = tokens[b * T_ + t];
    const float4* er = (const float4*)(embed + (size_t)tok * E_);
    float acc[16];
#pragma unroll
    for (int j = 0; j < 16; ++j) acc[j] = bias[grp * H_ + s * 16 + j];
    for (int e4 = 0; e4 < E_ / 4; ++e4) {
      float4 em = er[e4];
#pragma unroll
      for (int eo = 0; eo < 4; ++eo) {
        float ev = reinterpret_cast<const float*>(&em)[eo];
        const int k = e4 * 4 + eo;
#pragma unroll
        for (int j = 0; j < 16; ++j) acc[j] += ev * Wl[wl_idx(k, grp * 16 + j)];
      }
    }
#pragma unroll
    for (int j = 0; j < 16; ++j) Xl[xl_idx(grp * 16 + j, t)] = f2bf(acc[j]);
  };

  // Load the lane's 64 weights in ROTATED order so do_dot's register indices
  // are all compile-time (scratch-free; the R9-R16 lesson).
  auto load_wreg = [&] {
#pragma unroll
    for (int i = 0; i < 16; ++i) {
      const int q = (i + 2 * kch) & 15;    // runtime math feeding an LDS ADDR — ok
#pragma unroll
      for (int j = 0; j < 4; ++j)
        wreg[i * 4 + j] = Wl[wl_idx(kch * 64 + q * 4 + j, cc)];
    }
#pragma unroll
    for (int kk = 0; kk < 64; ++kk) asm volatile("" : "+v"(wreg[kk]));  // pin
  };

  // Per-THREAD poll of OWN float. Fast path: 2-deep pipelined asm poll —
  // two outstanding sc0 sc1 loads staggered ~half a MALL latency apart,
  // checked alternately => sampling period ~450cy instead of ~900cy.
  // Bounded; timeout -> proven agent-atomic loop + fast path off forever.
  auto poll_own = [&](unsigned gen) {
    const u32 par = (gen >> 1) & 1u;
    const u32* p = img + (gen & 1u) * 4096 + bH + tid;
    u32 v = 0u;
    bool got = false;
    if (fastOk) {
      u32 v0, v1, t0; u32 cnt, ok;
      asm volatile(
        "s_movk_i32 %[cnt], 0x200\n\t"
        "global_load_dword %[v0], %[p], off sc0 sc1\n\t"
        "s_sleep 6\n\t"
        "global_load_dword %[v1], %[p], off sc0 sc1\n"
        "Lp%=:\n\t"
        "s_waitcnt vmcnt(1)\n\t"                 // v0 sample ready
        "v_xor_b32 %[t0], %[par], %[v0]\n\t"
        "v_and_b32 %[t0], 1, %[t0]\n\t"
        "v_cmp_eq_u32 vcc, 0, %[t0]\n\t"         // lanes matching
        "s_andn2_b64 vcc, exec, vcc\n\t"         // SCC = any lane missing
        "s_cbranch_scc0 Lh0%=\n\t"
        "global_load_dword %[v0], %[p], off sc0 sc1\n\t"
        "s_waitcnt vmcnt(1)\n\t"                 // v1 sample ready
        "v_xor_b32 %[t0], %[par], %[v1]\n\t"
        "v_and_b32 %[t0], 1, %[t0]\n\t"
        "v_cmp_eq_u32 vcc, 0, %[t0]\n\t"
        "s_andn2_b64 vcc, exec, vcc\n\t"
        "s_cbranch_scc0 Lh1%=\n\t"
        "global_load_dword %[v1], %[p], off sc0 sc1\n\t"
        "s_add_i32 %[cnt], %[cnt], -1\n\t"
        "s_cmp_gt_i32 %[cnt], 0\n\t"
        "s_cbranch_scc1 Lp%=\n\t"
        "s_waitcnt vmcnt(0)\n\t"                 // timeout: drain, ok=0
        "s_mov_b32 %[ok], 0\n\t"
        "s_branch Le%=\n"
        "Lh1%=:\n\t"
        "s_waitcnt vmcnt(0)\n\t"                 // drain v0's reissue FIRST
        "v_mov_b32 %[v0], %[v1]\n\t"
        "s_mov_b32 %[ok], 1\n\t"
        "s_branch Le%=\n"
        "Lh0%=:\n\t"
        "s_waitcnt vmcnt(0)\n\t"                 // drain v1's in-flight load
        "s_mov_b32 %[ok], 1\n"
        "Le%=:"
        : [v0] "=&v"(v0), [v1] "=&v"(v1), [t0] "=&v"(t0),
          [cnt] "=&s"(cnt), [ok] "=&s"(ok)
        : [p] "v"(p), [par] "s"(par)
        : "vcc", "memory");
      if (ok) { v = v0; got = true; }
      else    fastOk = false;              // fail-safe: never retry asm path
    }
    if (!got) {                            // proven agent-atomic fallback
      for (;;) {
        v = __hip_atomic_load(p, __ATOMIC_RELAXED, __HIP_MEMORY_SCOPE_AGENT);
        if ((v & 1u) == par) break;
        if (--wd < 0) break;               // fail fast, not hang
        __builtin_amdgcn_s_sleep(1);
      }
    }
    h_lds[tid] = __uint_as_float(v);       // tag bit kept (1 ulp, harmless)
  };

  // Full dot for this lane's col over shared h_lds. h4[q]: LDS read, runtime
  // addr fine (kch-rotation de-conflicts banks); wreg[i*4+j]: COMPILE-TIME
  // register index (scratch-free).
  auto do_dot = [&]() -> float {
    float a0 = 0.f, a1 = 0.f, a2 = 0.f, a3 = 0.f;
    const float4* h4 = (const float4*)(h_lds + kch * 64);
#pragma unroll
    for (int i = 0; i < 16; ++i) {
      const int q = (i + 2 * kch) & 15;    // matches load_wreg's rotation
      float4 hv = h4[q];
      a0 += hv.x * wreg[i * 4 + 0];
      a1 += hv.y * wreg[i * 4 + 1];
      a2 += hv.z * wreg[i * 4 + 2];
      a3 += hv.w * wreg[i * 4 + 3];
    }
    float sum = (a0 + a1) + (a2 + a3);
    sum += __shfl_xor(sum, 8);
    sum += __shfl_xor(sum, 16);
    sum += __shfl_xor(sum, 32);
    return sum;                            // full pre-dot for col cc, all lanes
  };

  // ---------------- Phase A1 + shared weights
  computeX(Wih_s, b_s);
  __syncthreads();
  stage_W(Whh_s, H_, s, Wl);
  __syncthreads();
  load_wreg();

  float c_reg = 0.f, Mreg = 0.f;

  // ---------------- Phase B: shared LSTM; publishes gens 1..128.
  for (int t = 0; t < T_; ++t) {
    float pre = 0.f;
    if (t > 0) {
      poll_own((unsigned)t);
      __syncthreads();                     // barrier 1: h_lds complete
      pre = do_dot();
    }
    if (l < 8) pre += bf2f(Xl[xl_idx(cc, t)]);   // only shfl sources need X
    float gi = __shfl(pre, d),     gf = __shfl(pre, 2 + d),
          gg = __shfl(pre, 4 + d), go = __shfl(pre, 6 + d);
    float cn = sigf(gf) * c_reg + sigf(gi) * tanh_f(gg);
    float hn = sigf(go) * tanh_f(cn);
    c_reg = cn;
    if (l < 2) hOut[2 * wv + l] = hn;      // wave owns h-cols s*16+2wv+{0,1}
    __syncthreads();                       // barrier 2: hOut complete
    if (tid < 16) {                        // SINGLE 16-lane 64B publish
      const unsigned gw = (unsigned)t + 1u;
      u32 hb = (__float_as_uint(hOut[tid]) & ~1u) | ((gw >> 1) & 1u);
      __hip_atomic_store(img + (gw & 1u) * 4096 + bH + s * 16 + tid, hb,
                         __ATOMIC_RELAXED, __HIP_MEMORY_SCOPE_AGENT);
    }
  }

  // ---------------- M = h_last @ Wmh_t (consume gen 128)
  __syncthreads();
  stage_W(Wmh_t, H_, s, Wl);
  __syncthreads();
  load_wreg();
  poll_own(128u);
  __syncthreads();
  Mreg = do_dot();                         // M for col cc (consistent replicas)

  // ---------------- Phase A2 + task weights
  __syncthreads();
  computeX(Wih_t, b_t);
  __syncthreads();
  stage_W(Whh_t, H_, s, Wl);
  __syncthreads();
  load_wreg();

  // ---------------- Phase C: task LSTM; gens 129..255; out every step
  c_reg = 0.f;
  for (int t = 0; t < T_; ++t) {
    float pre = 0.f;
    if (t > 0) {
      poll_own(128u + (unsigned)t);
      __syncthreads();                     // barrier 1
      pre = do_dot();
    }
    if (l < 8) pre += bf2f(Xl[xl_idx(cc, t)]) + Mreg;
    float gi = __shfl(pre, d),     gf = __shfl(pre, 2 + d),
          gg = __shfl(pre, 4 + d), go = __shfl(pre, 6 + d);
    float cn = sigf(gf) * c_reg + sigf(gi) * tanh_f(gg);
    float hn = sigf(go) * tanh_f(cn);
    c_reg = cn;
    if (l < 2) hOut[2 * wv + l] = hn;
    __syncthreads();                       // barrier 2
    if (tid < 16) {                        // publish FIRST (ring-critical), then out
      if (t < T_ - 1) {
        const unsigned gw = 129u + (unsigned)t;
        u32 hb = (__float_as_uint(hOut[tid]) & ~1u) | ((gw >> 1) & 1u);
        __hip_atomic_store(img + (gw & 1u) * 4096 + bH + s * 16 + tid, hb,
                           __ATOMIC_RELAXED, __HIP_MEMORY_SCOPE_AGENT);
      }
      out[b * (T_ * H_) + t * H_ + s * 16 + tid] = hOut[tid];  // 64B coalesced
    }
  }
}

extern "C" void kernel_launch(void* const* d_in, const int* in_sizes, int n_in,
                              void* d_out, int out_size, void* d_ws, size_t ws_size,
                              hipStream_t stream) {
  const int*   tokens = (const int*)d_in[0];
  // d_in[1] = TASK (unused)
  const float* embed  = (const float*)d_in[2];
  const float* Wih_s  = (const float*)d_in[3];
  const float* Whh_s  = (const float*)d_in[4];
  const float* b_s    = (const float*)d_in[5];
  // d_in[6..9] = Ws_w, Ws_b, Us_w, Us_b -> dead (attention collapses)
  const float* Wih_t  = (const float*)d_in[10];
  const float* Whh_t  = (const float*)d_in[11];
  const float* Wmh_t  = (const float*)d_in[12];
  const float* b_t    = (const float*)d_in[13];
  float* out = (float*)d_out;
  u32*   img = (u32*)d_ws;

  hipLaunchKernelGGL(init_ws, dim3(8), dim3(1024), 0, stream, img);
  hipLaunchKernelGGL(lstm_all, dim3(NWG), dim3(NTHR), 0, stream,
                     tokens, embed, Wih_s, Whh_s, b_s,
                     Wih_t, Whh_t, Wmh_t, b_t, out, img);
}